// Round 1
// baseline (185.320 us; speedup 1.0000x reference)
//
#include <hip/hip_runtime.h>

#define NHEAD 12
#define EMB 768
#define HDD 64
#define SEQ 2048
#define NBATCH 2

typedef __attribute__((ext_vector_type(4))) float f32x4;
typedef __attribute__((ext_vector_type(8))) short short8;

static __device__ __forceinline__ short bf16s(float f) {
    unsigned u = __builtin_bit_cast(unsigned, f);
    u = (u + 0x7fffu + ((u >> 16) & 1u)) >> 16;
    return (short)u;
}

// ---- x f32 -> bf16 (row-major [4096][768]) ----
__global__ void k_cvt_x(const float* __restrict__ x, short* __restrict__ xb) {
    const int i = (blockIdx.x * 256 + threadIdx.x) * 8;
    const f32x4* s = (const f32x4*)(x + i);
    f32x4 a = s[0], b = s[1];
    short8 o;
    o[0] = bf16s(a[0]); o[1] = bf16s(a[1]); o[2] = bf16s(a[2]); o[3] = bf16s(a[3]);
    o[4] = bf16s(b[0]); o[5] = bf16s(b[1]); o[6] = bf16s(b[2]); o[7] = bf16s(b[3]);
    *(short8*)(xb + i) = o;
}

// ---- Wq/Wk/Wv [12][768][64] f32 -> Wt[(h*64+d)][768 e] bf16 ----
__global__ void k_cvt_whead(const float* __restrict__ W, short* __restrict__ Wt) {
    __shared__ float tile[64][65];
    const int h = blockIdx.x, e0 = blockIdx.y * 64;
    const int t = threadIdx.x;
    const int r = t >> 2, c0 = (t & 3) * 16;
    const float* src = W + (h * EMB + e0 + r) * HDD + c0;
#pragma unroll
    for (int i = 0; i < 16; ++i) tile[r][c0 + i] = src[i];
    __syncthreads();
    short* dst = Wt + (h * HDD + r) * EMB + e0 + c0;  // r acts as d here
#pragma unroll
    for (int i = 0; i < 16; ++i) dst[i] = bf16s(tile[c0 + i][r]);
}

// ---- Wo [768 k][768 n] f32 -> WoT[n][k] bf16 ----
__global__ void k_cvt_wo(const float* __restrict__ W, short* __restrict__ Wt) {
    __shared__ float tile[64][65];
    const int k0 = blockIdx.x * 64, n0 = blockIdx.y * 64;
    const int t = threadIdx.x;
    const int r = t >> 2, c0 = (t & 3) * 16;
    const float* src = W + (k0 + r) * EMB + n0 + c0;
#pragma unroll
    for (int i = 0; i < 16; ++i) tile[r][c0 + i] = src[i];
    __syncthreads();
    short* dst = Wt + (n0 + r) * EMB + k0 + c0;
#pragma unroll
    for (int i = 0; i < 16; ++i) dst[i] = bf16s(tile[c0 + i][r]);
}

// ---- GEMM: C[m][n] = sum_k A[m][k]*Bt[n][k].  M=4096, N=768, K=768.
// MODE 0: bf16 out scattered to [B,H,S,D] (z selects Wq/Wk/Wv -> Q/K/V)
// MODE 1: f32 out row-major [m][768] + bias
#define GK EMB
#define LDT 48

template <int MODE>
__global__ __launch_bounds__(256) void k_gemm(
        const short* __restrict__ A, const short* __restrict__ B0,
        const short* __restrict__ B1, const short* __restrict__ B2,
        short* __restrict__ D0, short* __restrict__ D1, short* __restrict__ D2,
        const float* __restrict__ bias, float* __restrict__ Fout) {
    __shared__ alignas(16) short As[128 * LDT];
    __shared__ alignas(16) short Bs[128 * LDT];
    const int t = threadIdx.x, lane = t & 63, wave = t >> 6;
    const int m0 = blockIdx.y * 128, n0 = blockIdx.x * 128;
    const short* Bt = B0;
    short* Dst = D0;
    if (MODE == 0 && blockIdx.z == 1) { Bt = B1; Dst = D1; }
    if (MODE == 0 && blockIdx.z == 2) { Bt = B2; Dst = D2; }

    const int srow = t >> 1, scol = (t & 1) * 16;
    const short* gA = A + (m0 + srow) * GK + scol;
    const short* gB = Bt + (n0 + srow) * GK + scol;
    short* sA = As + srow * LDT + scol;
    short* sB = Bs + srow * LDT + scol;

    const int wm = (wave >> 1) * 64, wn = (wave & 1) * 64;
    const int fr = lane & 15, fk = (lane >> 4) * 8;

    f32x4 acc[4][4];
#pragma unroll
    for (int i = 0; i < 4; ++i)
#pragma unroll
        for (int j = 0; j < 4; ++j)
#pragma unroll
            for (int e = 0; e < 4; ++e) acc[i][j][e] = 0.f;

    for (int kk = 0; kk < GK; kk += 32) {
        short8 a0 = *(const short8*)(gA + kk);
        short8 a1 = *(const short8*)(gA + kk + 8);
        short8 b0 = *(const short8*)(gB + kk);
        short8 b1 = *(const short8*)(gB + kk + 8);
        __syncthreads();
        *(short8*)(sA) = a0; *(short8*)(sA + 8) = a1;
        *(short8*)(sB) = b0; *(short8*)(sB + 8) = b1;
        __syncthreads();
        short8 af[4], bfr[4];
#pragma unroll
        for (int i = 0; i < 4; ++i)
            af[i] = *(const short8*)(As + (wm + i * 16 + fr) * LDT + fk);
#pragma unroll
        for (int j = 0; j < 4; ++j)
            bfr[j] = *(const short8*)(Bs + (wn + j * 16 + fr) * LDT + fk);
#pragma unroll
        for (int i = 0; i < 4; ++i) {
#pragma unroll
            for (int j = 0; j < 4; ++j)
                acc[i][j] = __builtin_amdgcn_mfma_f32_16x16x32_bf16(af[i], bfr[j], acc[i][j], 0, 0, 0);
        }
    }

    const int r0 = (lane >> 4) * 4;
#pragma unroll
    for (int i = 0; i < 4; ++i) {
#pragma unroll
        for (int j = 0; j < 4; ++j) {
#pragma unroll
            for (int r = 0; r < 4; ++r) {
                const int m = m0 + wm + i * 16 + r0 + r;
                const int n = n0 + wn + j * 16 + fr;
                const float v = acc[i][j][r];
                if (MODE == 0) {
                    const int bb = m >> 11, ss = m & 2047;
                    const int hh = n >> 6, dd = n & 63;
                    Dst[((bb * NHEAD + hh) * SEQ + ss) * HDD + dd] = bf16s(v);
                } else {
                    Fout[m * EMB + n] = v + bias[n];
                }
            }
        }
    }
}

// ---- causal flash attention: Q,K,V [B,H,S,64] bf16 -> O [B,S,768] bf16 ----
__global__ __launch_bounds__(256) void k_attn(
        const short* __restrict__ Q, const short* __restrict__ K,
        const short* __restrict__ V, short* __restrict__ O) {
    __shared__ alignas(16) short Ks[64 * 72];
    __shared__ alignas(16) short Vt[64 * 72];
    __shared__ alignas(16) short Ps[4][16 * 72];
    const int qb = blockIdx.x, h = blockIdx.y, b = blockIdx.z;
    const int t = threadIdx.x, lane = t & 63, wave = t >> 6;
    const int q0 = qb * 64;
    const long base = (long)(b * NHEAD + h) * SEQ * HDD;
    const short* Qg = Q + base;
    const short* Kg = K + base;
    const short* Vg = V + base;
    const int fr = lane & 15, fk = (lane >> 4) * 8;
    const int r0 = (lane >> 4) * 4;

    // Q fragments held in registers for the whole kernel (A-frag: row = lane&15)
    short8 qf0 = *(const short8*)(Qg + (q0 + wave * 16 + fr) * HDD + fk);
    short8 qf1 = *(const short8*)(Qg + (q0 + wave * 16 + fr) * HDD + 32 + fk);

    f32x4 oacc[4];
#pragma unroll
    for (int i = 0; i < 4; ++i)
#pragma unroll
        for (int e = 0; e < 4; ++e) oacc[i][e] = 0.f;
    float mrun[4] = {-1e30f, -1e30f, -1e30f, -1e30f};
    float lrun[4] = {0.f, 0.f, 0.f, 0.f};

    const int srow = t & 63, sq = t >> 6;
    short* Pw = Ps[wave];

    for (int kt = 0; kt <= qb; ++kt) {
        const int k0 = kt * 64;
        short8 kv0 = *(const short8*)(Kg + (k0 + srow) * HDD + sq * 16);
        short8 kv1 = *(const short8*)(Kg + (k0 + srow) * HDD + sq * 16 + 8);
        short8 vv0 = *(const short8*)(Vg + (k0 + srow) * HDD + sq * 16);
        short8 vv1 = *(const short8*)(Vg + (k0 + srow) * HDD + sq * 16 + 8);
        __syncthreads();  // previous iteration's readers done
        *(short8*)(Ks + srow * 72 + sq * 16) = kv0;
        *(short8*)(Ks + srow * 72 + sq * 16 + 8) = kv1;
#pragma unroll
        for (int i = 0; i < 8; ++i) Vt[(sq * 16 + i) * 72 + srow] = vv0[i];
#pragma unroll
        for (int i = 0; i < 8; ++i) Vt[(sq * 16 + 8 + i) * 72 + srow] = vv1[i];
        __syncthreads();

        // S = Q K^T (16 q-rows x 64 keys per wave)
        f32x4 sacc[4];
#pragma unroll
        for (int nt = 0; nt < 4; ++nt)
#pragma unroll
            for (int e = 0; e < 4; ++e) sacc[nt][e] = 0.f;
#pragma unroll
        for (int nt = 0; nt < 4; ++nt) {
            short8 kf0 = *(const short8*)(Ks + (nt * 16 + fr) * 72 + fk);
            short8 kf1 = *(const short8*)(Ks + (nt * 16 + fr) * 72 + 32 + fk);
            sacc[nt] = __builtin_amdgcn_mfma_f32_16x16x32_bf16(qf0, kf0, sacc[nt], 0, 0, 0);
            sacc[nt] = __builtin_amdgcn_mfma_f32_16x16x32_bf16(qf1, kf1, sacc[nt], 0, 0, 0);
        }

        // online softmax in C-layout: row=(lane>>4)*4+reg, col=lane&15
        float p[4][4], tmax[4] = {-1e30f, -1e30f, -1e30f, -1e30f};
#pragma unroll
        for (int nt = 0; nt < 4; ++nt) {
            const int key = k0 + nt * 16 + fr;
#pragma unroll
            for (int r = 0; r < 4; ++r) {
                float s = sacc[nt][r] * 0.125f;
                if (key > q0 + wave * 16 + r0 + r) s = -1e30f;
                p[nt][r] = s;
                tmax[r] = fmaxf(tmax[r], s);
            }
        }
#pragma unroll
        for (int off = 1; off < 16; off <<= 1) {
#pragma unroll
            for (int r = 0; r < 4; ++r)
                tmax[r] = fmaxf(tmax[r], __shfl_xor(tmax[r], off, 64));
        }
        float corr[4], rsum[4];
#pragma unroll
        for (int r = 0; r < 4; ++r) {
            const float mnew = fmaxf(mrun[r], tmax[r]);
            corr[r] = __expf(mrun[r] - mnew);
            mrun[r] = mnew;
            rsum[r] = 0.f;
        }
#pragma unroll
        for (int nt = 0; nt < 4; ++nt) {
#pragma unroll
            for (int r = 0; r < 4; ++r) {
                const float e = __expf(p[nt][r] - mrun[r]);
                p[nt][r] = e;
                rsum[r] += e;
            }
        }
#pragma unroll
        for (int off = 1; off < 16; off <<= 1) {
#pragma unroll
            for (int r = 0; r < 4; ++r)
                rsum[r] += __shfl_xor(rsum[r], off, 64);
        }
#pragma unroll
        for (int r = 0; r < 4; ++r) lrun[r] = lrun[r] * corr[r] + rsum[r];
#pragma unroll
        for (int dt = 0; dt < 4; ++dt)
#pragma unroll
            for (int r = 0; r < 4; ++r) oacc[dt][r] *= corr[r];
        // P -> LDS (per-wave region), absolute key indexing keeps A/B k-maps consistent
#pragma unroll
        for (int nt = 0; nt < 4; ++nt) {
#pragma unroll
            for (int r = 0; r < 4; ++r)
                Pw[(r0 + r) * 72 + nt * 16 + fr] = bf16s(p[nt][r]);
        }
        __syncthreads();
        // O += P V
#pragma unroll
        for (int kc = 0; kc < 2; ++kc) {
            short8 pf = *(const short8*)(Pw + fr * 72 + kc * 32 + fk);
#pragma unroll
            for (int dt = 0; dt < 4; ++dt) {
                short8 vf = *(const short8*)(Vt + (dt * 16 + fr) * 72 + kc * 32 + fk);
                oacc[dt] = __builtin_amdgcn_mfma_f32_16x16x32_bf16(pf, vf, oacc[dt], 0, 0, 0);
            }
        }
    }

#pragma unroll
    for (int dt = 0; dt < 4; ++dt) {
#pragma unroll
        for (int r = 0; r < 4; ++r) {
            const int qq = q0 + wave * 16 + r0 + r;
            const int dd = dt * 16 + fr;
            O[(long)(b * SEQ + qq) * (NHEAD * HDD) + h * HDD + dd] = bf16s(oacc[dt][r] / lrun[r]);
        }
    }
}

extern "C" void kernel_launch(void* const* d_in, const int* in_sizes, int n_in,
                              void* d_out, int out_size, void* d_ws, size_t ws_size,
                              hipStream_t stream) {
    const float* x  = (const float*)d_in[0];
    const float* Wq = (const float*)d_in[1];
    const float* Wk = (const float*)d_in[2];
    const float* Wv = (const float*)d_in[3];
    const float* Wo = (const float*)d_in[4];
    const float* bo = (const float*)d_in[5];
    float* out = (float*)d_out;

    char* ws = (char*)d_ws;
    short* xb  = (short*)(ws + 0);         // 4096x768 bf16   = 6,291,456 B
    short* WqT = (short*)(ws + 6291456);   // 768x768 bf16    = 1,179,648 B
    short* WkT = (short*)(ws + 7471104);
    short* WvT = (short*)(ws + 8650752);
    short* WoT = (short*)(ws + 9830400);
    short* Qb  = (short*)(ws + 11010048);  // [2,12,2048,64] bf16 = 6,291,456 B
    short* Kb  = (short*)(ws + 17301504);
    short* Vb  = (short*)(ws + 23592960);
    short* Ob  = (short*)(ws + 29884416);  // [4096,768] bf16
    // total ws use: 36,175,872 B

    k_cvt_x<<<dim3(1536), dim3(256), 0, stream>>>(x, xb);
    k_cvt_whead<<<dim3(12, 12), dim3(256), 0, stream>>>(Wq, WqT);
    k_cvt_whead<<<dim3(12, 12), dim3(256), 0, stream>>>(Wk, WkT);
    k_cvt_whead<<<dim3(12, 12), dim3(256), 0, stream>>>(Wv, WvT);
    k_cvt_wo<<<dim3(12, 12), dim3(256), 0, stream>>>(Wo, WoT);
    k_gemm<0><<<dim3(6, 32, 3), dim3(256), 0, stream>>>(
        xb, WqT, WkT, WvT, Qb, Kb, Vb, (const float*)nullptr, (float*)nullptr);
    k_attn<<<dim3(32, 12, 2), dim3(256), 0, stream>>>(Qb, Kb, Vb, Ob);
    k_gemm<1><<<dim3(6, 32, 1), dim3(256), 0, stream>>>(
        Ob, WoT, (const short*)nullptr, (const short*)nullptr,
        (short*)nullptr, (short*)nullptr, (short*)nullptr, bo, out);
}

// Round 2
// 119.084 us; speedup vs baseline: 1.5562x; 1.5562x over previous
//
#include <hip/hip_runtime.h>

#define NHEAD 12
#define EMB 768
#define HDD 64
#define SEQ 2048

typedef __attribute__((ext_vector_type(4))) float f32x4;
typedef __attribute__((ext_vector_type(8))) short short8;
typedef unsigned int u32;

#define GLL16(g, l)                                                            \
    __builtin_amdgcn_global_load_lds(                                          \
        (const __attribute__((address_space(1))) u32*)(g),                     \
        (__attribute__((address_space(3))) u32*)(l), 16, 0, 0)

static __device__ __forceinline__ short bf16s(float f) {
    unsigned u = __builtin_bit_cast(unsigned, f);
    u = (u + 0x7fffu + ((u >> 16) & 1u)) >> 16;
    return (short)u;
}

// ---- x f32 -> bf16 (row-major [4096][768]) ----
__global__ void k_cvt_x(const float* __restrict__ x, short* __restrict__ xb) {
    const int i = (blockIdx.x * 256 + threadIdx.x) * 8;
    const f32x4* s = (const f32x4*)(x + i);
    f32x4 a = s[0], b = s[1];
    short8 o;
    o[0] = bf16s(a[0]); o[1] = bf16s(a[1]); o[2] = bf16s(a[2]); o[3] = bf16s(a[3]);
    o[4] = bf16s(b[0]); o[5] = bf16s(b[1]); o[6] = bf16s(b[2]); o[7] = bf16s(b[3]);
    *(short8*)(xb + i) = o;
}

// ---- Wq/Wk/Wv [12][768][64] f32 -> Wt[(h*64+d)][768 e] bf16 (z picks q/k/v) ----
__global__ void k_cvt_whead(const float* __restrict__ Wq, const float* __restrict__ Wk,
                            const float* __restrict__ Wv, short* __restrict__ WqT,
                            short* __restrict__ WkT, short* __restrict__ WvT) {
    const float* W = blockIdx.z == 0 ? Wq : (blockIdx.z == 1 ? Wk : Wv);
    short* Wt = blockIdx.z == 0 ? WqT : (blockIdx.z == 1 ? WkT : WvT);
    __shared__ float tile[64][65];
    const int h = blockIdx.x, e0 = blockIdx.y * 64;
    const int t = threadIdx.x;
    const int r = t >> 2, c0 = (t & 3) * 16;
    const float* src = W + (h * EMB + e0 + r) * HDD + c0;
#pragma unroll
    for (int i = 0; i < 16; ++i) tile[r][c0 + i] = src[i];
    __syncthreads();
    short* dst = Wt + (h * HDD + r) * EMB + e0 + c0;  // r acts as d here
#pragma unroll
    for (int i = 0; i < 16; ++i) dst[i] = bf16s(tile[c0 + i][r]);
}

// ---- Wo [768 k][768 n] f32 -> WoT[n][k] bf16 ----
__global__ void k_cvt_wo(const float* __restrict__ W, short* __restrict__ Wt) {
    __shared__ float tile[64][65];
    const int k0 = blockIdx.x * 64, n0 = blockIdx.y * 64;
    const int t = threadIdx.x;
    const int r = t >> 2, c0 = (t & 3) * 16;
    const float* src = W + (k0 + r) * EMB + n0 + c0;
#pragma unroll
    for (int i = 0; i < 16; ++i) tile[r][c0 + i] = src[i];
    __syncthreads();
    short* dst = Wt + (n0 + r) * EMB + k0 + c0;
#pragma unroll
    for (int i = 0; i < 16; ++i) dst[i] = bf16s(tile[c0 + i][r]);
}

// ---- GEMM (m97 structure): C[m][n] = sum_k A[m][k]*Bt[n][k], K=768, BK=32.
// MODE 0: z=0 -> Q*0.125 scattered [B,H,S,D]; z=1 -> K scattered [B,H,S,D];
//         z=2 -> A/B swapped, out = V^T [B,H,D,S] (coalesced).
// MODE 1: f32 out row-major [m][768] + bias.
template <int MODE>
__global__ __launch_bounds__(256) void k_gemm(
        const short* __restrict__ xb, const short* __restrict__ Wt0,
        const short* __restrict__ Wt1, const short* __restrict__ Wt2,
        short* __restrict__ Qo, short* __restrict__ Ko, short* __restrict__ Vo,
        const float* __restrict__ bias, float* __restrict__ Fout) {
    __shared__ alignas(16) short As[128 * 32];
    __shared__ alignas(16) short Bs[128 * 32];
    const int t = threadIdx.x, lane = t & 63, wave = t >> 6;
    const int z = (MODE == 0) ? blockIdx.z : 0;
    const short* Ap;
    const short* Bp;
    int m0, n0;
    if (MODE == 1) {
        Ap = xb; Bp = Wt0; m0 = blockIdx.y * 128; n0 = blockIdx.x * 128;
    } else if (z == 0) {
        Ap = xb; Bp = Wt0; m0 = blockIdx.y * 128; n0 = blockIdx.x * 128;
    } else if (z == 1) {
        Ap = xb; Bp = Wt1; m0 = blockIdx.y * 128; n0 = blockIdx.x * 128;
    } else {  // V^T: A = WvT (768 rows), B = xb (4096 rows)
        Ap = Wt2; Bp = xb; m0 = blockIdx.x * 128; n0 = blockIdx.y * 128;
    }

    const short* gA = Ap + (long)(m0 + wave * 32 + (lane >> 2)) * EMB + (lane & 3) * 8;
    const short* gB = Bp + (long)(n0 + wave * 32 + (lane >> 2)) * EMB + (lane & 3) * 8;
    short* lA = As + (wave * 32) * 32;
    short* lB = Bs + (wave * 32) * 32;

    const int wm = (wave >> 1) * 64, wn = (wave & 1) * 64;
    const int fr = lane & 15, hi = lane >> 4, fk = hi * 8;

    f32x4 acc[4][4];
#pragma unroll
    for (int i = 0; i < 4; ++i)
#pragma unroll
        for (int j = 0; j < 4; ++j)
#pragma unroll
            for (int e = 0; e < 4; ++e) acc[i][j][e] = 0.f;

    for (int kk = 0; kk < EMB; kk += 32) {
        __syncthreads();
        GLL16(gA + kk, lA);
        GLL16(gA + kk + 16 * EMB, lA + 16 * 32);
        GLL16(gB + kk, lB);
        GLL16(gB + kk + 16 * EMB, lB + 16 * 32);
        __syncthreads();
        short8 af[4], bfq[4];
#pragma unroll
        for (int i = 0; i < 4; ++i)
            af[i] = *(const short8*)(As + (wm + i * 16 + fr) * 32 + fk);
#pragma unroll
        for (int j = 0; j < 4; ++j)
            bfq[j] = *(const short8*)(Bs + (wn + j * 16 + fr) * 32 + fk);
#pragma unroll
        for (int i = 0; i < 4; ++i)
#pragma unroll
            for (int j = 0; j < 4; ++j)
                acc[i][j] = __builtin_amdgcn_mfma_f32_16x16x32_bf16(af[i], bfq[j], acc[i][j], 0, 0, 0);
    }

    const int r0 = hi * 4;
#pragma unroll
    for (int i = 0; i < 4; ++i) {
#pragma unroll
        for (int j = 0; j < 4; ++j) {
            const int nbase = n0 + wn + j * 16 + fr;
            float bj = 0.f;
            if (MODE == 1) bj = bias[nbase];
#pragma unroll
            for (int r = 0; r < 4; ++r) {
                const int m = m0 + wm + i * 16 + r0 + r;
                float v = acc[i][j][r];
                if (MODE == 0) {
                    if (z == 2) {
                        // m = h*64+d, n = b*2048+s
                        const int hh = m >> 6, dd = m & 63;
                        const int bb = nbase >> 11, ss = nbase & 2047;
                        Vo[(long)((bb * NHEAD + hh) * HDD + dd) * SEQ + ss] = bf16s(v);
                    } else {
                        const int bb = m >> 11, ss = m & 2047;
                        const int hh = nbase >> 6, dd = nbase & 63;
                        short* Dst = (z == 0) ? Qo : Ko;
                        if (z == 0) v *= 0.125f;  // fold 1/sqrt(64) into Q
                        Dst[(long)((bb * NHEAD + hh) * SEQ + ss) * HDD + dd] = bf16s(v);
                    }
                } else {
                    Fout[(long)m * EMB + nbase] = v + bj;
                }
            }
        }
    }
}

// ---- causal flash attention (swapped-operand form) ----
// Q,K: [B,H,S,64] bf16 (Q pre-scaled); VT: [B,H,64,S] bf16 -> O [B,S,768] bf16
__global__ __launch_bounds__(256) void k_attn(
        const short* __restrict__ Q, const short* __restrict__ K,
        const short* __restrict__ VT, short* __restrict__ O) {
    __shared__ alignas(16) short Ks[64 * 72];      // [key][d]
    __shared__ alignas(16) short Vt[64 * 72];      // [d][key]
    __shared__ alignas(16) short Ps[4][16 * 72];   // per-wave P[q][key]; reused as O-transpose buf
    const int qb = (int)gridDim.x - 1 - (int)blockIdx.x;  // longest blocks first
    const int h = blockIdx.y, b = blockIdx.z;
    const int t = threadIdx.x, lane = t & 63, wave = t >> 6;
    const int q0 = qb * 64;
    const long base = (long)(b * NHEAD + h) * SEQ * HDD;
    const short* Qg = Q + base;
    const short* Kg = K + base;
    const short* Vg = VT + base;  // [64][2048]
    const int fr = lane & 15, hi = lane >> 4, fk = hi * 8, r0 = hi * 4;
    const int myq = q0 + wave * 16 + fr;

    // Q fragments (B-frag, rows = q), resident all kernel
    const short8 qf0 = *(const short8*)(Qg + (long)(q0 + wave * 16 + fr) * HDD + fk);
    const short8 qf1 = *(const short8*)(Qg + (long)(q0 + wave * 16 + fr) * HDD + 32 + fk);

    f32x4 oaccT[4];  // O^T tiles: row d = dt*16+r0+r, col q = fr
#pragma unroll
    for (int i = 0; i < 4; ++i)
#pragma unroll
        for (int e = 0; e < 4; ++e) oaccT[i][e] = 0.f;
    float mrun = -3e38f, lrun = 0.f;

    const int srow = t >> 2, sc = (t & 3) * 16;
    short* Pw = Ps[wave];

    // prefetch tile 0
    const short* Kt0 = Kg + (long)srow * HDD + sc;
    const short* Vt0 = Vg + (long)srow * SEQ + sc;
    short8 kv0 = *(const short8*)(Kt0);
    short8 kv1 = *(const short8*)(Kt0 + 8);
    short8 vv0 = *(const short8*)(Vt0);
    short8 vv1 = *(const short8*)(Vt0 + 8);

    for (int kt = 0; kt <= qb; ++kt) {
        const int k0 = kt * 64;
        __syncthreads();  // all waves done reading previous tile
        *(short8*)(Ks + srow * 72 + sc) = kv0;
        *(short8*)(Ks + srow * 72 + sc + 8) = kv1;
        *(short8*)(Vt + srow * 72 + sc) = vv0;
        *(short8*)(Vt + srow * 72 + sc + 8) = vv1;
        if (kt < qb) {  // prefetch next tile; hides under compute below
            const short* Kn = Kt0 + (long)(k0 + 64) * HDD;
            const short* Vn = Vt0 + (k0 + 64);
            kv0 = *(const short8*)(Kn);
            kv1 = *(const short8*)(Kn + 8);
            vv0 = *(const short8*)(Vn);
            vv1 = *(const short8*)(Vn + 8);
        }
        __syncthreads();

        // S^T = K Q^T : tile nt covers keys nt*16..+15 (rows), q = fr (col)
        f32x4 st[4];
#pragma unroll
        for (int nt = 0; nt < 4; ++nt) {
#pragma unroll
            for (int e = 0; e < 4; ++e) st[nt][e] = 0.f;
            const short8 kf0 = *(const short8*)(Ks + (nt * 16 + fr) * 72 + fk);
            const short8 kf1 = *(const short8*)(Ks + (nt * 16 + fr) * 72 + 32 + fk);
            st[nt] = __builtin_amdgcn_mfma_f32_16x16x32_bf16(kf0, qf0, st[nt], 0, 0, 0);
            st[nt] = __builtin_amdgcn_mfma_f32_16x16x32_bf16(kf1, qf1, st[nt], 0, 0, 0);
        }

        // softmax: lane holds 16 keys of one q-row (q = fr)
        float p[4][4];
        float pmax = -3e38f;
        if (kt == qb) {  // only the diagonal tile needs masking (block-uniform branch)
#pragma unroll
            for (int nt = 0; nt < 4; ++nt)
#pragma unroll
                for (int r = 0; r < 4; ++r) {
                    float s = st[nt][r];
                    if (k0 + nt * 16 + r0 + r > myq) s = -3e38f;
                    p[nt][r] = s;
                    pmax = fmaxf(pmax, s);
                }
        } else {
#pragma unroll
            for (int nt = 0; nt < 4; ++nt)
#pragma unroll
                for (int r = 0; r < 4; ++r) {
                    p[nt][r] = st[nt][r];
                    pmax = fmaxf(pmax, st[nt][r]);
                }
        }
        pmax = fmaxf(pmax, __shfl_xor(pmax, 16, 64));
        pmax = fmaxf(pmax, __shfl_xor(pmax, 32, 64));
        const float mnew = fmaxf(mrun, pmax);
        const float corr = __expf(mrun - mnew);
        mrun = mnew;
        float rsum = 0.f;
#pragma unroll
        for (int nt = 0; nt < 4; ++nt)
#pragma unroll
            for (int r = 0; r < 4; ++r) {
                const float e = __expf(p[nt][r] - mnew);
                p[nt][r] = e;
                rsum += e;
            }
        rsum += __shfl_xor(rsum, 16, 64);
        rsum += __shfl_xor(rsum, 32, 64);
        lrun = lrun * corr + rsum;
#pragma unroll
        for (int dt = 0; dt < 4; ++dt)
#pragma unroll
            for (int e = 0; e < 4; ++e) oaccT[dt][e] *= corr;

        // P[q][key] -> per-wave LDS (no barrier: own-wave write->read)
#pragma unroll
        for (int nt = 0; nt < 4; ++nt)
#pragma unroll
            for (int r = 0; r < 4; ++r)
                Pw[fr * 72 + nt * 16 + r0 + r] = bf16s(p[nt][r]);

        // O^T += V^T P^T : A = V^T rows d, B = P rows q
#pragma unroll
        for (int kc = 0; kc < 2; ++kc) {
            const short8 pf = *(const short8*)(Pw + fr * 72 + kc * 32 + fk);
#pragma unroll
            for (int dt = 0; dt < 4; ++dt) {
                const short8 vf = *(const short8*)(Vt + (dt * 16 + fr) * 72 + kc * 32 + fk);
                oaccT[dt] = __builtin_amdgcn_mfma_f32_16x16x32_bf16(vf, pf, oaccT[dt], 0, 0, 0);
            }
        }
    }

    // transpose O back through LDS (reuse Ps; rows wave*16+fr land in own segment)
    short* Os = &Ps[0][0];
    const float inv = 1.0f / lrun;
#pragma unroll
    for (int dt = 0; dt < 4; ++dt)
#pragma unroll
        for (int r = 0; r < 4; ++r)
            Os[(wave * 16 + fr) * 72 + dt * 16 + r0 + r] = bf16s(oaccT[dt][r] * inv);
    __syncthreads();
    const short8 o0 = *(const short8*)(Os + srow * 72 + sc);
    const short8 o1 = *(const short8*)(Os + srow * 72 + sc + 8);
    short* Og = O + (long)(b * SEQ + q0 + srow) * EMB + h * HDD + sc;
    *(short8*)Og = o0;
    *(short8*)(Og + 8) = o1;
}

extern "C" void kernel_launch(void* const* d_in, const int* in_sizes, int n_in,
                              void* d_out, int out_size, void* d_ws, size_t ws_size,
                              hipStream_t stream) {
    const float* x  = (const float*)d_in[0];
    const float* Wq = (const float*)d_in[1];
    const float* Wk = (const float*)d_in[2];
    const float* Wv = (const float*)d_in[3];
    const float* Wo = (const float*)d_in[4];
    const float* bo = (const float*)d_in[5];
    float* out = (float*)d_out;

    char* ws = (char*)d_ws;
    short* xb  = (short*)(ws + 0);         // 4096x768 bf16   = 6,291,456 B
    short* WqT = (short*)(ws + 6291456);   // 768x768 bf16    = 1,179,648 B
    short* WkT = (short*)(ws + 7471104);
    short* WvT = (short*)(ws + 8650752);
    short* WoT = (short*)(ws + 9830400);
    short* Qb  = (short*)(ws + 11010048);  // [2,12,2048,64] bf16
    short* Kb  = (short*)(ws + 17301504);  // [2,12,2048,64]
    short* VTb = (short*)(ws + 23592960);  // [2,12,64,2048] (transposed)
    short* Ob  = (short*)(ws + 29884416);  // [4096,768] bf16

    k_cvt_x<<<dim3(1536), dim3(256), 0, stream>>>(x, xb);
    k_cvt_whead<<<dim3(12, 12, 3), dim3(256), 0, stream>>>(Wq, Wk, Wv, WqT, WkT, WvT);
    k_cvt_wo<<<dim3(12, 12), dim3(256), 0, stream>>>(Wo, WoT);
    k_gemm<0><<<dim3(6, 32, 3), dim3(256), 0, stream>>>(
        xb, WqT, WkT, WvT, Qb, Kb, VTb, (const float*)nullptr, (float*)nullptr);
    k_attn<<<dim3(32, 12, 2), dim3(256), 0, stream>>>(Qb, Kb, VTb, Ob);
    k_gemm<1><<<dim3(6, 32, 1), dim3(256), 0, stream>>>(
        Ob, WoT, (const short*)nullptr, (const short*)nullptr,
        (short*)nullptr, (short*)nullptr, (short*)nullptr, bo, out);
}

// Round 6
// 116.626 us; speedup vs baseline: 1.5890x; 1.0211x over previous
//
#include <hip/hip_runtime.h>

#define NHEAD 12
#define EMB 768
#define HDD 64
#define SEQ 2048

typedef __attribute__((ext_vector_type(4))) float f32x4;
typedef __attribute__((ext_vector_type(8))) short short8;
typedef unsigned int u32;

#define GLL16(g, l)                                                            \
    __builtin_amdgcn_global_load_lds(                                          \
        (const __attribute__((address_space(1))) u32*)(g),                     \
        (__attribute__((address_space(3))) u32*)(l), 16, 0, 0)

static __device__ __forceinline__ short bf16s(float f) {
    unsigned u = __builtin_bit_cast(unsigned, f);
    u = (u + 0x7fffu + ((u >> 16) & 1u)) >> 16;
    return (short)u;
}

// ---- x f32 -> bf16 (row-major [4096][768]) ----
__global__ void k_cvt_x(const float* __restrict__ x, short* __restrict__ xb) {
    const int i = (blockIdx.x * 256 + threadIdx.x) * 8;
    const f32x4* s = (const f32x4*)(x + i);
    f32x4 a = s[0], b = s[1];
    short8 o;
    o[0] = bf16s(a[0]); o[1] = bf16s(a[1]); o[2] = bf16s(a[2]); o[3] = bf16s(a[3]);
    o[4] = bf16s(b[0]); o[5] = bf16s(b[1]); o[6] = bf16s(b[2]); o[7] = bf16s(b[3]);
    *(short8*)(xb + i) = o;
}

// ---- Wq/Wk/Wv [12][768][64] f32 -> Wt[(h*64+d)][768 e] bf16 (z picks q/k/v) ----
__global__ void k_cvt_whead(const float* __restrict__ Wq, const float* __restrict__ Wk,
                            const float* __restrict__ Wv, short* __restrict__ WqT,
                            short* __restrict__ WkT, short* __restrict__ WvT) {
    const float* W = blockIdx.z == 0 ? Wq : (blockIdx.z == 1 ? Wk : Wv);
    short* Wt = blockIdx.z == 0 ? WqT : (blockIdx.z == 1 ? WkT : WvT);
    __shared__ float tile[64][65];
    const int h = blockIdx.x, e0 = blockIdx.y * 64;
    const int t = threadIdx.x;
    const int r = t >> 2, c0 = (t & 3) * 16;
    const float* src = W + (h * EMB + e0 + r) * HDD + c0;
#pragma unroll
    for (int i = 0; i < 16; ++i) tile[r][c0 + i] = src[i];
    __syncthreads();
    short* dst = Wt + (h * HDD + r) * EMB + e0 + c0;  // r acts as d here
#pragma unroll
    for (int i = 0; i < 16; ++i) dst[i] = bf16s(tile[c0 + i][r]);
}

// ---- Wo [768 k][768 n] f32 -> WoT[n][k] bf16 ----
__global__ void k_cvt_wo(const float* __restrict__ W, short* __restrict__ Wt) {
    __shared__ float tile[64][65];
    const int k0 = blockIdx.x * 64, n0 = blockIdx.y * 64;
    const int t = threadIdx.x;
    const int r = t >> 2, c0 = (t & 3) * 16;
    const float* src = W + (k0 + r) * EMB + n0 + c0;
#pragma unroll
    for (int i = 0; i < 16; ++i) tile[r][c0 + i] = src[i];
    __syncthreads();
    short* dst = Wt + (n0 + r) * EMB + k0 + c0;
#pragma unroll
    for (int i = 0; i < 16; ++i) dst[i] = bf16s(tile[c0 + i][r]);
}

// ---- GEMM (m97 structure): C[m][n] = sum_k A[m][k]*Bt[n][k], K=768, BK=32.
// MODE 0: z=0 -> Q*0.125 scattered [B,H,S,D]; z=1 -> K scattered;
//         z=2 -> A/B swapped, out = V^T [B,H,D,S] (coalesced).
// MODE 1: f32 out row-major [m][768] + bias.
template <int MODE>
__global__ __launch_bounds__(256) void k_gemm(
        const short* __restrict__ xb, const short* __restrict__ Wt0,
        const short* __restrict__ Wt1, const short* __restrict__ Wt2,
        short* __restrict__ Qo, short* __restrict__ Ko, short* __restrict__ Vo,
        const float* __restrict__ bias, float* __restrict__ Fout) {
    __shared__ alignas(16) short As[128 * 32];
    __shared__ alignas(16) short Bs[128 * 32];
    const int t = threadIdx.x, lane = t & 63, wave = t >> 6;
    const int z = (MODE == 0) ? blockIdx.z : 0;
    const short* Ap;
    const short* Bp;
    int m0, n0;
    if (MODE == 1) {
        Ap = xb; Bp = Wt0; m0 = blockIdx.y * 128; n0 = blockIdx.x * 128;
    } else if (z == 0) {
        Ap = xb; Bp = Wt0; m0 = blockIdx.y * 128; n0 = blockIdx.x * 128;
    } else if (z == 1) {
        Ap = xb; Bp = Wt1; m0 = blockIdx.y * 128; n0 = blockIdx.x * 128;
    } else {  // V^T: A = WvT (768 rows), B = xb (4096 rows)
        Ap = Wt2; Bp = xb; m0 = blockIdx.x * 128; n0 = blockIdx.y * 128;
    }

    const short* gA = Ap + (long)(m0 + wave * 32 + (lane >> 2)) * EMB + (lane & 3) * 8;
    const short* gB = Bp + (long)(n0 + wave * 32 + (lane >> 2)) * EMB + (lane & 3) * 8;
    short* lA = As + (wave * 32) * 32;
    short* lB = Bs + (wave * 32) * 32;

    const int wm = (wave >> 1) * 64, wn = (wave & 1) * 64;
    const int fr = lane & 15, hi = lane >> 4, fk = hi * 8;

    f32x4 acc[4][4];
#pragma unroll
    for (int i = 0; i < 4; ++i)
#pragma unroll
        for (int j = 0; j < 4; ++j)
#pragma unroll
            for (int e = 0; e < 4; ++e) acc[i][j][e] = 0.f;

    for (int kk = 0; kk < EMB; kk += 32) {
        __syncthreads();
        GLL16(gA + kk, lA);
        GLL16(gA + kk + 16 * EMB, lA + 16 * 32);
        GLL16(gB + kk, lB);
        GLL16(gB + kk + 16 * EMB, lB + 16 * 32);
        __syncthreads();
        short8 af[4], bfq[4];
#pragma unroll
        for (int i = 0; i < 4; ++i)
            af[i] = *(const short8*)(As + (wm + i * 16 + fr) * 32 + fk);
#pragma unroll
        for (int j = 0; j < 4; ++j)
            bfq[j] = *(const short8*)(Bs + (wn + j * 16 + fr) * 32 + fk);
#pragma unroll
        for (int i = 0; i < 4; ++i)
#pragma unroll
            for (int j = 0; j < 4; ++j)
                acc[i][j] = __builtin_amdgcn_mfma_f32_16x16x32_bf16(af[i], bfq[j], acc[i][j], 0, 0, 0);
    }

    const int r0 = hi * 4;
#pragma unroll
    for (int i = 0; i < 4; ++i) {
#pragma unroll
        for (int j = 0; j < 4; ++j) {
            const int nbase = n0 + wn + j * 16 + fr;
            float bj = 0.f;
            if (MODE == 1) bj = bias[nbase];
#pragma unroll
            for (int r = 0; r < 4; ++r) {
                const int m = m0 + wm + i * 16 + r0 + r;
                float v = acc[i][j][r];
                if (MODE == 0) {
                    if (z == 2) {
                        const int hh = m >> 6, dd = m & 63;
                        const int bb = nbase >> 11, ss = nbase & 2047;
                        Vo[(long)((bb * NHEAD + hh) * HDD + dd) * SEQ + ss] = bf16s(v);
                    } else {
                        const int bb = m >> 11, ss = m & 2047;
                        const int hh = nbase >> 6, dd = nbase & 63;
                        short* Dst = (z == 0) ? Qo : Ko;
                        if (z == 0) v *= 0.125f;  // fold 1/sqrt(64) into Q
                        Dst[(long)((bb * NHEAD + hh) * SEQ + ss) * HDD + dd] = bf16s(v);
                    }
                } else {
                    Fout[(long)m * EMB + nbase] = v + bj;
                }
            }
        }
    }
}

// ---- causal flash attention (swapped-operand form), QBLK=128 ----
// Round-6 discipline: this is EXACTLY the round-2 passing kernel plus one
// change: each wave owns 2 q-subtiles (QBLK 64->128). LDS-P path, shfl_xor
// reductions, expf, per-tile rescale all kept as proven.
// Q,K: [B,H,S,64] bf16 (Q pre-scaled by 0.125); VT: [B,H,64,S] -> O [B,S,768] bf16
__global__ __launch_bounds__(256) void k_attn(
        const short* __restrict__ Q, const short* __restrict__ K,
        const short* __restrict__ VT, short* __restrict__ O) {
    __shared__ alignas(16) short Ks[64 * 72];          // [key][d]
    __shared__ alignas(16) short Vs[64 * 72];          // [d][key]
    __shared__ alignas(16) short Ps[4][2][16 * 72];    // per-wave, per-qi P[q][key]
    const int bh = blockIdx.x;
    const int h = bh % NHEAD, b = bh / NHEAD;
    const int qs = (int)gridDim.y - 1 - (int)blockIdx.y;  // longest first
    const int q0 = qs * 128;
    const int ntile = 2 * qs + 2;
    const int t = threadIdx.x, lane = t & 63, wave = t >> 6;
    const long base = (long)(b * NHEAD + h) * SEQ * HDD;
    const short* Qg = Q + base;
    const short* Kg = K + base;
    const short* Vg = VT + base;  // [64][2048]
    const int fr = lane & 15, hi = lane >> 4, fk = hi * 8, r0 = hi * 4;
    const int wq = q0 + wave * 32;

    // Q fragments (B-frag, rows = q), resident all kernel
    short8 qf[2][2];
#pragma unroll
    for (int qi = 0; qi < 2; ++qi)
#pragma unroll
        for (int c = 0; c < 2; ++c)
            qf[qi][c] = *(const short8*)(Qg + (long)(wq + qi * 16 + fr) * HDD + c * 32 + fk);

    f32x4 oacc[2][4];  // O^T tiles per qi: row d = dt*16+r0+r, col q = fr
#pragma unroll
    for (int qi = 0; qi < 2; ++qi)
#pragma unroll
        for (int i = 0; i < 4; ++i)
#pragma unroll
            for (int e = 0; e < 4; ++e) oacc[qi][i][e] = 0.f;
    float mrun[2] = {-3e38f, -3e38f}, lrun[2] = {0.f, 0.f};

    const int srow = t >> 2, sc = (t & 3) * 16;
    const short* Kt0 = Kg + (long)srow * HDD + sc;
    const short* Vt0 = Vg + (long)srow * SEQ + sc;
    short8 kv0 = *(const short8*)(Kt0);
    short8 kv1 = *(const short8*)(Kt0 + 8);
    short8 vv0 = *(const short8*)(Vt0);
    short8 vv1 = *(const short8*)(Vt0 + 8);

    for (int kt = 0; kt < ntile; ++kt) {
        const int k0 = kt * 64;
        __syncthreads();  // all waves done reading previous tile
        *(short8*)(Ks + srow * 72 + sc) = kv0;
        *(short8*)(Ks + srow * 72 + sc + 8) = kv1;
        *(short8*)(Vs + srow * 72 + sc) = vv0;
        *(short8*)(Vs + srow * 72 + sc + 8) = vv1;
        if (kt + 1 < ntile) {  // prefetch next tile; hides under compute below
            const short* Kn = Kt0 + (long)(k0 + 64) * HDD;
            const short* Vn = Vt0 + (k0 + 64);
            kv0 = *(const short8*)(Kn);
            kv1 = *(const short8*)(Kn + 8);
            vv0 = *(const short8*)(Vn);
            vv1 = *(const short8*)(Vn + 8);
        }
        __syncthreads();
        if (k0 > wq + 31) continue;  // wave-uniform: all this wave's rows < k0

        short8 kf[4][2];
#pragma unroll
        for (int nt = 0; nt < 4; ++nt)
#pragma unroll
            for (int c = 0; c < 2; ++c)
                kf[nt][c] = *(const short8*)(Ks + (nt * 16 + fr) * 72 + c * 32 + fk);

#pragma unroll
        for (int qi = 0; qi < 2; ++qi) {
            const int qbase = wq + qi * 16;
            // S^T = K Q^T : tile nt covers keys nt*16..+15 (rows), q = fr (col)
            f32x4 st[4];
#pragma unroll
            for (int nt = 0; nt < 4; ++nt) {
#pragma unroll
                for (int e = 0; e < 4; ++e) st[nt][e] = 0.f;
                st[nt] = __builtin_amdgcn_mfma_f32_16x16x32_bf16(kf[nt][0], qf[qi][0], st[nt], 0, 0, 0);
                st[nt] = __builtin_amdgcn_mfma_f32_16x16x32_bf16(kf[nt][1], qf[qi][1], st[nt], 0, 0, 0);
            }

            // softmax: lane holds 16 keys of one q-row (q = fr)
            float p[4][4];
            float pmax = -3e38f;
            if (k0 + 63 > qbase) {  // diagonal-overlap tile: apply causal mask
                const int myq = qbase + fr;
#pragma unroll
                for (int nt = 0; nt < 4; ++nt)
#pragma unroll
                    for (int r = 0; r < 4; ++r) {
                        float s = st[nt][r];
                        if (k0 + nt * 16 + r0 + r > myq) s = -3e38f;
                        p[nt][r] = s;
                        pmax = fmaxf(pmax, s);
                    }
            } else {
#pragma unroll
                for (int nt = 0; nt < 4; ++nt)
#pragma unroll
                    for (int r = 0; r < 4; ++r) {
                        p[nt][r] = st[nt][r];
                        pmax = fmaxf(pmax, st[nt][r]);
                    }
            }
            pmax = fmaxf(pmax, __shfl_xor(pmax, 16, 64));
            pmax = fmaxf(pmax, __shfl_xor(pmax, 32, 64));
            const float mnew = fmaxf(mrun[qi], pmax);
            const float corr = __expf(mrun[qi] - mnew);
            mrun[qi] = mnew;
            float rsum = 0.f;
#pragma unroll
            for (int nt = 0; nt < 4; ++nt)
#pragma unroll
                for (int r = 0; r < 4; ++r) {
                    const float e = __expf(p[nt][r] - mnew);
                    p[nt][r] = e;
                    rsum += e;
                }
            rsum += __shfl_xor(rsum, 16, 64);
            rsum += __shfl_xor(rsum, 32, 64);
            lrun[qi] = lrun[qi] * corr + rsum;
#pragma unroll
            for (int dt = 0; dt < 4; ++dt)
#pragma unroll
                for (int e = 0; e < 4; ++e) oacc[qi][dt][e] *= corr;

            // P[q][key] -> per-wave LDS region (own-wave write->read, no barrier)
            short* Pw = &Ps[wave][qi][0];
#pragma unroll
            for (int nt = 0; nt < 4; ++nt)
#pragma unroll
                for (int r = 0; r < 4; ++r)
                    Pw[fr * 72 + nt * 16 + r0 + r] = bf16s(p[nt][r]);
        }

        // O^T += V^T P^T for both qi (shared vf reads)
#pragma unroll
        for (int kc = 0; kc < 2; ++kc) {
            const short8 pf0 = *(const short8*)(&Ps[wave][0][fr * 72 + kc * 32 + fk]);
            const short8 pf1 = *(const short8*)(&Ps[wave][1][fr * 72 + kc * 32 + fk]);
#pragma unroll
            for (int dt = 0; dt < 4; ++dt) {
                const short8 vf = *(const short8*)(Vs + (dt * 16 + fr) * 72 + kc * 32 + fk);
                oacc[0][dt] = __builtin_amdgcn_mfma_f32_16x16x32_bf16(vf, pf0, oacc[0][dt], 0, 0, 0);
                oacc[1][dt] = __builtin_amdgcn_mfma_f32_16x16x32_bf16(vf, pf1, oacc[1][dt], 0, 0, 0);
            }
        }
    }

    // transpose O^T back via LDS (each wave writes its own Ps slice) and store
    short* Os = &Ps[0][0][0];  // flat [128][72]
    __syncthreads();
#pragma unroll
    for (int qi = 0; qi < 2; ++qi) {
        const float iv = 1.0f / lrun[qi];
#pragma unroll
        for (int dt = 0; dt < 4; ++dt)
#pragma unroll
            for (int r = 0; r < 4; ++r)
                Os[(wave * 32 + qi * 16 + fr) * 72 + dt * 16 + r0 + r] = bf16s(oacc[qi][dt][r] * iv);
    }
    __syncthreads();
    {
        // 2 threads/row, 32 cols each => four short8 stores
        const int row = t >> 1, half = t & 1;
        const short8 o0 = *(const short8*)(Os + row * 72 + half * 32);
        const short8 o1 = *(const short8*)(Os + row * 72 + half * 32 + 8);
        const short8 o2 = *(const short8*)(Os + row * 72 + half * 32 + 16);
        const short8 o3 = *(const short8*)(Os + row * 72 + half * 32 + 24);
        short* Og = O + (long)(b * SEQ + q0 + row) * EMB + h * HDD + half * 32;
        *(short8*)Og = o0;
        *(short8*)(Og + 8) = o1;
        *(short8*)(Og + 16) = o2;
        *(short8*)(Og + 24) = o3;
    }
}

extern "C" void kernel_launch(void* const* d_in, const int* in_sizes, int n_in,
                              void* d_out, int out_size, void* d_ws, size_t ws_size,
                              hipStream_t stream) {
    const float* x  = (const float*)d_in[0];
    const float* Wq = (const float*)d_in[1];
    const float* Wk = (const float*)d_in[2];
    const float* Wv = (const float*)d_in[3];
    const float* Wo = (const float*)d_in[4];
    const float* bo = (const float*)d_in[5];
    float* out = (float*)d_out;

    char* ws = (char*)d_ws;
    short* xb  = (short*)(ws + 0);         // 4096x768 bf16
    short* WqT = (short*)(ws + 6291456);
    short* WkT = (short*)(ws + 7471104);
    short* WvT = (short*)(ws + 8650752);
    short* WoT = (short*)(ws + 9830400);
    short* Qb  = (short*)(ws + 11010048);  // [2,12,2048,64] bf16 (pre-scaled)
    short* Kb  = (short*)(ws + 17301504);  // [2,12,2048,64]
    short* VTb = (short*)(ws + 23592960);  // [2,12,64,2048] (transposed)
    short* Ob  = (short*)(ws + 29884416);  // [4096,768] bf16

    k_cvt_x<<<dim3(1536), dim3(256), 0, stream>>>(x, xb);
    k_cvt_whead<<<dim3(12, 12, 3), dim3(256), 0, stream>>>(Wq, Wk, Wv, WqT, WkT, WvT);
    k_cvt_wo<<<dim3(12, 12), dim3(256), 0, stream>>>(Wo, WoT);
    k_gemm<0><<<dim3(6, 32, 3), dim3(256), 0, stream>>>(
        xb, WqT, WkT, WvT, Qb, Kb, VTb, (const float*)nullptr, (float*)nullptr);
    k_attn<<<dim3(24, 16), dim3(256), 0, stream>>>(Qb, Kb, VTb, Ob);
    k_gemm<1><<<dim3(6, 32, 1), dim3(256), 0, stream>>>(
        Ob, WoT, (const short*)nullptr, (const short*)nullptr,
        (short*)nullptr, (short*)nullptr, (short*)nullptr, bo, out);
}

// Round 7
// 106.800 us; speedup vs baseline: 1.7352x; 1.0920x over previous
//
#include <hip/hip_runtime.h>

#define NHEAD 12
#define EMB 768
#define HDD 64
#define SEQ 2048

typedef __attribute__((ext_vector_type(4))) float f32x4;
typedef __attribute__((ext_vector_type(8))) short short8;
typedef unsigned int u32;

#define GLL16(g, l)                                                            \
    __builtin_amdgcn_global_load_lds(                                          \
        (const __attribute__((address_space(1))) u32*)(g),                     \
        (__attribute__((address_space(3))) u32*)(l), 16, 0, 0)

static __device__ __forceinline__ short bf16s(float f) {
    unsigned u = __builtin_bit_cast(unsigned, f);
    u = (u + 0x7fffu + ((u >> 16) & 1u)) >> 16;
    return (short)u;
}

// ---- x f32 -> bf16 (row-major [4096][768]) ----
__global__ void k_cvt_x(const float* __restrict__ x, short* __restrict__ xb) {
    const int i = (blockIdx.x * 256 + threadIdx.x) * 8;
    const f32x4* s = (const f32x4*)(x + i);
    f32x4 a = s[0], b = s[1];
    short8 o;
    o[0] = bf16s(a[0]); o[1] = bf16s(a[1]); o[2] = bf16s(a[2]); o[3] = bf16s(a[3]);
    o[4] = bf16s(b[0]); o[5] = bf16s(b[1]); o[6] = bf16s(b[2]); o[7] = bf16s(b[3]);
    *(short8*)(xb + i) = o;
}

// ---- Wq/Wk/Wv [12][768][64] f32 -> Wt[(h*64+d)][768 e] bf16 (z picks q/k/v) ----
__global__ void k_cvt_whead(const float* __restrict__ Wq, const float* __restrict__ Wk,
                            const float* __restrict__ Wv, short* __restrict__ WqT,
                            short* __restrict__ WkT, short* __restrict__ WvT) {
    const float* W = blockIdx.z == 0 ? Wq : (blockIdx.z == 1 ? Wk : Wv);
    short* Wt = blockIdx.z == 0 ? WqT : (blockIdx.z == 1 ? WkT : WvT);
    __shared__ float tile[64][65];
    const int h = blockIdx.x, e0 = blockIdx.y * 64;
    const int t = threadIdx.x;
    const int r = t >> 2, c0 = (t & 3) * 16;
    const float* src = W + (h * EMB + e0 + r) * HDD + c0;
#pragma unroll
    for (int i = 0; i < 16; ++i) tile[r][c0 + i] = src[i];
    __syncthreads();
    short* dst = Wt + (h * HDD + r) * EMB + e0 + c0;  // r acts as d here
#pragma unroll
    for (int i = 0; i < 16; ++i) dst[i] = bf16s(tile[c0 + i][r]);
}

// ---- Wo [768 k][768 n] f32 -> WoT[n][k] bf16 ----
__global__ void k_cvt_wo(const float* __restrict__ W, short* __restrict__ Wt) {
    __shared__ float tile[64][65];
    const int k0 = blockIdx.x * 64, n0 = blockIdx.y * 64;
    const int t = threadIdx.x;
    const int r = t >> 2, c0 = (t & 3) * 16;
    const float* src = W + (k0 + r) * EMB + n0 + c0;
#pragma unroll
    for (int i = 0; i < 16; ++i) tile[r][c0 + i] = src[i];
    __syncthreads();
    short* dst = Wt + (n0 + r) * EMB + k0 + c0;
#pragma unroll
    for (int i = 0; i < 16; ++i) dst[i] = bf16s(tile[c0 + i][r]);
}

// ---- GEMM (m97 structure): C[m][n] = sum_k A[m][k]*Bt[n][k], K=768, BK=32.
// MODE 0: z=0 -> Q*0.125 scattered [B,H,S,D]; z=1 -> K scattered;
//         z=2 -> A/B swapped, out = V^T [B,H,D,S] (coalesced).
// MODE 1: f32 out row-major [m][768] + bias.
template <int MODE>
__global__ __launch_bounds__(256) void k_gemm(
        const short* __restrict__ xb, const short* __restrict__ Wt0,
        const short* __restrict__ Wt1, const short* __restrict__ Wt2,
        short* __restrict__ Qo, short* __restrict__ Ko, short* __restrict__ Vo,
        const float* __restrict__ bias, float* __restrict__ Fout) {
    __shared__ alignas(16) short As[128 * 32];
    __shared__ alignas(16) short Bs[128 * 32];
    const int t = threadIdx.x, lane = t & 63, wave = t >> 6;
    const int z = (MODE == 0) ? blockIdx.z : 0;
    const short* Ap;
    const short* Bp;
    int m0, n0;
    if (MODE == 1) {
        Ap = xb; Bp = Wt0; m0 = blockIdx.y * 128; n0 = blockIdx.x * 128;
    } else if (z == 0) {
        Ap = xb; Bp = Wt0; m0 = blockIdx.y * 128; n0 = blockIdx.x * 128;
    } else if (z == 1) {
        Ap = xb; Bp = Wt1; m0 = blockIdx.y * 128; n0 = blockIdx.x * 128;
    } else {  // V^T: A = WvT (768 rows), B = xb (4096 rows)
        Ap = Wt2; Bp = xb; m0 = blockIdx.x * 128; n0 = blockIdx.y * 128;
    }

    const short* gA = Ap + (long)(m0 + wave * 32 + (lane >> 2)) * EMB + (lane & 3) * 8;
    const short* gB = Bp + (long)(n0 + wave * 32 + (lane >> 2)) * EMB + (lane & 3) * 8;
    short* lA = As + (wave * 32) * 32;
    short* lB = Bs + (wave * 32) * 32;

    const int wm = (wave >> 1) * 64, wn = (wave & 1) * 64;
    const int fr = lane & 15, hi = lane >> 4, fk = hi * 8;

    f32x4 acc[4][4];
#pragma unroll
    for (int i = 0; i < 4; ++i)
#pragma unroll
        for (int j = 0; j < 4; ++j)
#pragma unroll
            for (int e = 0; e < 4; ++e) acc[i][j][e] = 0.f;

    for (int kk = 0; kk < EMB; kk += 32) {
        __syncthreads();
        GLL16(gA + kk, lA);
        GLL16(gA + kk + 16 * EMB, lA + 16 * 32);
        GLL16(gB + kk, lB);
        GLL16(gB + kk + 16 * EMB, lB + 16 * 32);
        __syncthreads();
        short8 af[4], bfq[4];
#pragma unroll
        for (int i = 0; i < 4; ++i)
            af[i] = *(const short8*)(As + (wm + i * 16 + fr) * 32 + fk);
#pragma unroll
        for (int j = 0; j < 4; ++j)
            bfq[j] = *(const short8*)(Bs + (wn + j * 16 + fr) * 32 + fk);
#pragma unroll
        for (int i = 0; i < 4; ++i)
#pragma unroll
            for (int j = 0; j < 4; ++j)
                acc[i][j] = __builtin_amdgcn_mfma_f32_16x16x32_bf16(af[i], bfq[j], acc[i][j], 0, 0, 0);
    }

    const int r0 = hi * 4;
#pragma unroll
    for (int i = 0; i < 4; ++i) {
#pragma unroll
        for (int j = 0; j < 4; ++j) {
            const int nbase = n0 + wn + j * 16 + fr;
            float bj = 0.f;
            if (MODE == 1) bj = bias[nbase];
#pragma unroll
            for (int r = 0; r < 4; ++r) {
                const int m = m0 + wm + i * 16 + r0 + r;
                float v = acc[i][j][r];
                if (MODE == 0) {
                    if (z == 2) {
                        const int hh = m >> 6, dd = m & 63;
                        const int bb = nbase >> 11, ss = nbase & 2047;
                        Vo[(long)((bb * NHEAD + hh) * HDD + dd) * SEQ + ss] = bf16s(v);
                    } else {
                        const int bb = m >> 11, ss = m & 2047;
                        const int hh = nbase >> 6, dd = nbase & 63;
                        short* Dst = (z == 0) ? Qo : Ko;
                        if (z == 0) v *= 0.125f;  // fold 1/sqrt(64) into Q
                        Dst[(long)((bb * NHEAD + hh) * SEQ + ss) * HDD + dd] = bf16s(v);
                    }
                } else {
                    Fout[(long)m * EMB + nbase] = v + bj;
                }
            }
        }
    }
}

// ---- causal flash attention (swapped-operand form) ----
// Round-7: 8 waves x 16 q-rows (QBLK=128), double-buffered K/V LDS with ONE
// barrier per tile; proven shfl/expf softmax and LDS-P path kept verbatim.
// Q,K: [B,H,S,64] bf16 (Q pre-scaled by 0.125); VT: [B,H,64,S] -> O [B,S,768] bf16
__global__ __launch_bounds__(512) void k_attn(
        const short* __restrict__ Q, const short* __restrict__ K,
        const short* __restrict__ VT, short* __restrict__ O) {
    __shared__ alignas(16) short Kbuf[2][64 * 72];   // [key][d]
    __shared__ alignas(16) short Vbuf[2][64 * 72];   // [d][key]
    __shared__ alignas(16) short Ps[8][16 * 72];     // per-wave P[q][key]; reused as O buf
    const int bh = blockIdx.x;
    const int h = bh % NHEAD, b = bh / NHEAD;
    const int qs = (int)gridDim.y - 1 - (int)blockIdx.y;  // longest first
    const int q0 = qs * 128;
    const int ntile = 2 * qs + 2;
    const int t = threadIdx.x, lane = t & 63, wave = t >> 6;
    const long base = (long)(b * NHEAD + h) * SEQ * HDD;
    const short* Qg = Q + base;
    const short* Kg = K + base;
    const short* Vg = VT + base;  // [64][2048]
    const int fr = lane & 15, hi = lane >> 4, fk = hi * 8, r0 = hi * 4;
    const int wq = q0 + wave * 16;  // this wave's 16 q-rows: wq..wq+15

    // Q fragments (B-frag, rows = q), resident all kernel
    short8 qf[2];
#pragma unroll
    for (int c = 0; c < 2; ++c)
        qf[c] = *(const short8*)(Qg + (long)(wq + fr) * HDD + c * 32 + fk);

    f32x4 oacc[4];  // O^T: row d = dt*16+r0+r, col q = fr
#pragma unroll
    for (int i = 0; i < 4; ++i)
#pragma unroll
        for (int e = 0; e < 4; ++e) oacc[i][e] = 0.f;
    float mrun = -3e38f, lrun = 0.f;

    // staging: 512 threads, one short8 each for K and V per tile
    const int srow = t >> 3, scol = (t & 7) * 8;
    const short* KgS = Kg + (long)srow * HDD + scol;   // + k0*HDD per tile
    const short* VgS = Vg + (long)srow * SEQ + scol;   // + k0 per tile
    short* Pw = &Ps[wave][0];

    // prologue: tile 0 -> buf0; prefetch tile 1 into regs
    short8 kvR = *(const short8*)(KgS);
    short8 vvR = *(const short8*)(VgS);
    *(short8*)(&Kbuf[0][srow * 72 + scol]) = kvR;
    *(short8*)(&Vbuf[0][srow * 72 + scol]) = vvR;
    if (ntile > 1) {
        kvR = *(const short8*)(KgS + (long)64 * HDD);
        vvR = *(const short8*)(VgS + 64);
    }
    __syncthreads();

    for (int kt = 0; kt < ntile; ++kt) {
        const int k0 = kt * 64;
        const int cur = kt & 1;
        if (kt + 1 < ntile) {
            // write prefetched tile kt+1 into the other buffer
            *(short8*)(&Kbuf[cur ^ 1][srow * 72 + scol]) = kvR;
            *(short8*)(&Vbuf[cur ^ 1][srow * 72 + scol]) = vvR;
            if (kt + 2 < ntile) {  // issue tile kt+2 loads early (hide under compute)
                kvR = *(const short8*)(KgS + (long)(k0 + 128) * HDD);
                vvR = *(const short8*)(VgS + (k0 + 128));
            }
        }
        if (k0 <= wq + 15) {  // wave-uniform activity guard (no continue: keep barriers uniform)
            const short* Ks = &Kbuf[cur][0];
            const short* Vs = &Vbuf[cur][0];

            // S^T = K Q^T : tile nt covers keys nt*16..+15 (rows), q = fr (col)
            f32x4 st[4];
#pragma unroll
            for (int nt = 0; nt < 4; ++nt) {
                const short8 kf0 = *(const short8*)(Ks + (nt * 16 + fr) * 72 + fk);
                const short8 kf1 = *(const short8*)(Ks + (nt * 16 + fr) * 72 + 32 + fk);
#pragma unroll
                for (int e = 0; e < 4; ++e) st[nt][e] = 0.f;
                st[nt] = __builtin_amdgcn_mfma_f32_16x16x32_bf16(kf0, qf[0], st[nt], 0, 0, 0);
                st[nt] = __builtin_amdgcn_mfma_f32_16x16x32_bf16(kf1, qf[1], st[nt], 0, 0, 0);
            }

            // softmax: lane holds 16 keys of one q-row (q = fr)
            float p[4][4];
            float pmax = -3e38f;
            if (k0 + 63 > wq) {  // diagonal-overlap tile: apply causal mask
                const int myq = wq + fr;
#pragma unroll
                for (int nt = 0; nt < 4; ++nt)
#pragma unroll
                    for (int r = 0; r < 4; ++r) {
                        float s = st[nt][r];
                        if (k0 + nt * 16 + r0 + r > myq) s = -3e38f;
                        p[nt][r] = s;
                        pmax = fmaxf(pmax, s);
                    }
            } else {
#pragma unroll
                for (int nt = 0; nt < 4; ++nt)
#pragma unroll
                    for (int r = 0; r < 4; ++r) {
                        p[nt][r] = st[nt][r];
                        pmax = fmaxf(pmax, st[nt][r]);
                    }
            }
            pmax = fmaxf(pmax, __shfl_xor(pmax, 16, 64));
            pmax = fmaxf(pmax, __shfl_xor(pmax, 32, 64));
            const float mnew = fmaxf(mrun, pmax);
            const float corr = __expf(mrun - mnew);
            mrun = mnew;
            float rsum = 0.f;
#pragma unroll
            for (int nt = 0; nt < 4; ++nt)
#pragma unroll
                for (int r = 0; r < 4; ++r) {
                    const float e = __expf(p[nt][r] - mnew);
                    p[nt][r] = e;
                    rsum += e;
                }
            rsum += __shfl_xor(rsum, 16, 64);
            rsum += __shfl_xor(rsum, 32, 64);
            lrun = lrun * corr + rsum;
#pragma unroll
            for (int dt = 0; dt < 4; ++dt)
#pragma unroll
                for (int e = 0; e < 4; ++e) oacc[dt][e] *= corr;

            // P[q][key] -> per-wave LDS region (own-wave write->read, no barrier)
#pragma unroll
            for (int nt = 0; nt < 4; ++nt)
#pragma unroll
                for (int r = 0; r < 4; ++r)
                    Pw[fr * 72 + nt * 16 + r0 + r] = bf16s(p[nt][r]);

            // O^T += V^T P^T
#pragma unroll
            for (int kc = 0; kc < 2; ++kc) {
                const short8 pf = *(const short8*)(Pw + fr * 72 + kc * 32 + fk);
#pragma unroll
                for (int dt = 0; dt < 4; ++dt) {
                    const short8 vf = *(const short8*)(Vs + (dt * 16 + fr) * 72 + kc * 32 + fk);
                    oacc[dt] = __builtin_amdgcn_mfma_f32_16x16x32_bf16(vf, pf, oacc[dt], 0, 0, 0);
                }
            }
        }
        __syncthreads();  // buf[cur^1] writes visible; buf[cur] reads done
    }

    // transpose O^T back via LDS (Ps reused as flat [128][72]) and store
    short* Os = &Ps[0][0];
    const float iv = 1.0f / lrun;
#pragma unroll
    for (int dt = 0; dt < 4; ++dt)
#pragma unroll
        for (int r = 0; r < 4; ++r)
            Os[(wave * 16 + fr) * 72 + dt * 16 + r0 + r] = bf16s(oacc[dt][r] * iv);
    __syncthreads();
    {
        // 4 threads/row, 16 cols each => two short8 stores
        const int row = t >> 2, c0 = (t & 3) * 16;
        const short8 o0 = *(const short8*)(Os + row * 72 + c0);
        const short8 o1 = *(const short8*)(Os + row * 72 + c0 + 8);
        short* Og = O + (long)(b * SEQ + q0 + row) * EMB + h * HDD + c0;
        *(short8*)Og = o0;
        *(short8*)(Og + 8) = o1;
    }
}

extern "C" void kernel_launch(void* const* d_in, const int* in_sizes, int n_in,
                              void* d_out, int out_size, void* d_ws, size_t ws_size,
                              hipStream_t stream) {
    const float* x  = (const float*)d_in[0];
    const float* Wq = (const float*)d_in[1];
    const float* Wk = (const float*)d_in[2];
    const float* Wv = (const float*)d_in[3];
    const float* Wo = (const float*)d_in[4];
    const float* bo = (const float*)d_in[5];
    float* out = (float*)d_out;

    char* ws = (char*)d_ws;
    short* xb  = (short*)(ws + 0);         // 4096x768 bf16
    short* WqT = (short*)(ws + 6291456);
    short* WkT = (short*)(ws + 7471104);
    short* WvT = (short*)(ws + 8650752);
    short* WoT = (short*)(ws + 9830400);
    short* Qb  = (short*)(ws + 11010048);  // [2,12,2048,64] bf16 (pre-scaled)
    short* Kb  = (short*)(ws + 17301504);  // [2,12,2048,64]
    short* VTb = (short*)(ws + 23592960);  // [2,12,64,2048] (transposed)
    short* Ob  = (short*)(ws + 29884416);  // [4096,768] bf16

    k_cvt_x<<<dim3(1536), dim3(256), 0, stream>>>(x, xb);
    k_cvt_whead<<<dim3(12, 12, 3), dim3(256), 0, stream>>>(Wq, Wk, Wv, WqT, WkT, WvT);
    k_cvt_wo<<<dim3(12, 12), dim3(256), 0, stream>>>(Wo, WoT);
    k_gemm<0><<<dim3(6, 32, 3), dim3(256), 0, stream>>>(
        xb, WqT, WkT, WvT, Qb, Kb, VTb, (const float*)nullptr, (float*)nullptr);
    k_attn<<<dim3(24, 16), dim3(512), 0, stream>>>(Qb, Kb, VTb, Ob);
    k_gemm<1><<<dim3(6, 32, 1), dim3(256), 0, stream>>>(
        Ob, WoT, (const short*)nullptr, (const short*)nullptr,
        (short*)nullptr, (short*)nullptr, (short*)nullptr, bo, out);
}